// Round 1
// baseline (979.884 us; speedup 1.0000x reference)
//
#include <hip/hip_runtime.h>
#include <math.h>

constexpr int BATCH  = 65536;
constexpr int IN_DIM = 512;
constexpr int LATENT = 32;
constexpr int NTRIL  = 528;        // 32*33/2
constexpr float BN_EPS = 1e-5f;
constexpr float SLOPE  = 0.01f;

constexpr int RPB  = 64;           // batch rows per block
constexpr int SUBR = 8;            // rows per cov sub-batch (L_sh capacity)
constexpr int HSTR = 36;           // h_sh row stride (16B aligned, breaks pow2)
constexpr int LSTR = 36;           // stride of one L-row inside a batch-row's L
constexpr int LROW = LATENT * LSTR; // 1152 floats per batch row

__device__ __forceinline__ float leaky(float v) {
    return v >= 0.0f ? v : SLOPE * v;
}

extern "C" __global__ __launch_bounds__(256)
void pm_fused(const float* __restrict__ x,
              const float* __restrict__ W_enc,
              const float* __restrict__ b_enc,
              const float* __restrict__ bn_gamma,
              const float* __restrict__ bn_beta,
              const float* __restrict__ bn_mean,
              const float* __restrict__ bn_var,
              const float* __restrict__ W_mu,
              const float* __restrict__ b_mu,
              const float* __restrict__ W_ch,
              const float* __restrict__ b_ch,
              float* __restrict__ out)
{
    __shared__ float h_sh[RPB][HSTR];      // 9216 B
    __shared__ float L_sh[SUBR][LROW];     // 36864 B  (total 46080 B)

    const int t = threadIdx.x;
    const int row0 = blockIdx.x * RPB;

    float* __restrict__ h_out   = out;
    float* __restrict__ mu_out  = out + (size_t)BATCH * LATENT;
    float* __restrict__ cov_out = out + (size_t)2 * BATCH * LATENT;

    // ---------------- Phase 1: h = x @ W_enc, BN, leaky ----------------
    {
        const int c = t & 31;          // latent column
        const int g = t >> 5;          // 0..7 -> rows g*8 .. g*8+7
        const float4* __restrict__ xp =
            (const float4*)(x + (size_t)(row0 + g * 8) * IN_DIM);
        const float* __restrict__ Wc = W_enc + c;

        float acc[8];
        #pragma unroll
        for (int j = 0; j < 8; ++j) acc[j] = 0.0f;

        #pragma unroll 2
        for (int k4 = 0; k4 < IN_DIM / 4; ++k4) {
            const float w0 = Wc[(4 * k4 + 0) * LATENT];
            const float w1 = Wc[(4 * k4 + 1) * LATENT];
            const float w2 = Wc[(4 * k4 + 2) * LATENT];
            const float w3 = Wc[(4 * k4 + 3) * LATENT];
            #pragma unroll
            for (int j = 0; j < 8; ++j) {
                const float4 xv = xp[j * (IN_DIM / 4) + k4];
                acc[j] += xv.x * w0 + xv.y * w1 + xv.z * w2 + xv.w * w3;
            }
        }

        const float be = b_enc[c];
        const float gm = bn_gamma[c];
        const float bt = bn_beta[c];
        const float mn = bn_mean[c];
        const float iv = rsqrtf(bn_var[c] + BN_EPS);

        #pragma unroll
        for (int j = 0; j < 8; ++j) {
            float v = acc[j] + be;
            v = gm * (v - mn) * iv + bt;
            v = leaky(v);
            const int r = g * 8 + j;
            h_sh[r][c] = v;
            h_out[(size_t)(row0 + r) * LATENT + c] = v;
        }
    }
    __syncthreads();

    // ---------------- Phase 2: mus = leaky(h @ W_mu + b_mu) ----------------
    {
        const int c = t & 31;
        const int g = t >> 5;
        float wmu[LATENT];
        #pragma unroll
        for (int k = 0; k < LATENT; ++k) wmu[k] = W_mu[k * LATENT + c];
        const float bm = b_mu[c];
        #pragma unroll
        for (int j = 0; j < 8; ++j) {
            const int r = g * 8 + j;
            const float4* __restrict__ hr = (const float4*)&h_sh[r][0];
            float a = bm;
            #pragma unroll
            for (int k4 = 0; k4 < 8; ++k4) {
                const float4 hv = hr[k4];
                a += hv.x * wmu[4*k4+0] + hv.y * wmu[4*k4+1]
                   + hv.z * wmu[4*k4+2] + hv.w * wmu[4*k4+3];
            }
            mu_out[(size_t)(row0 + r) * LATENT + c] = leaky(a);
        }
    }
    // h_sh is read-only from here on; L_sh untouched so far -> no barrier needed.

    // ---------------- Phase 3: per sub-batch: elts -> L_sh, then cov ----------------
    #pragma unroll 1
    for (int sb = 0; sb < RPB / SUBR; ++sb) {
        const int rbl = sb * SUBR;

        // --- 3a: elts = leaky(h @ W_ch + b_ch), diag -> softplus-clip, into L_sh ---
        // job = (quad of 4 tril elems) x (half of the 8 rows); 264 jobs over 256 threads
        #pragma unroll 1
        for (int jid = t; jid < 2 * (NTRIL / 4); jid += 256) {
            const int q  = jid % (NTRIL / 4);   // 0..131
            const int rh = jid / (NTRIL / 4);   // 0..1 -> rows rh*4..rh*4+3
            const int j0 = 4 * q;

            float4 a[4];
            a[0] = make_float4(b_ch[j0+0], b_ch[j0+1], b_ch[j0+2], b_ch[j0+3]);
            a[1] = a[0]; a[2] = a[0]; a[3] = a[0];

            const float* __restrict__ wbase = W_ch + j0;
            #pragma unroll
            for (int kq = 0; kq < 8; ++kq) {
                float4 w[4];
                #pragma unroll
                for (int e = 0; e < 4; ++e)
                    w[e] = *(const float4*)(wbase + (4*kq + e) * NTRIL);
                #pragma unroll
                for (int rr = 0; rr < 4; ++rr) {
                    const float4 hv = *(const float4*)&h_sh[rbl + rh*4 + rr][4*kq];
                    a[rr].x += hv.x*w[0].x + hv.y*w[1].x + hv.z*w[2].x + hv.w*w[3].x;
                    a[rr].y += hv.x*w[0].y + hv.y*w[1].y + hv.z*w[2].y + hv.w*w[3].y;
                    a[rr].z += hv.x*w[0].z + hv.y*w[1].z + hv.z*w[2].z + hv.w*w[3].z;
                    a[rr].w += hv.x*w[0].w + hv.y*w[1].w + hv.z*w[2].w + hv.w*w[3].w;
                }
            }

            #pragma unroll
            for (int e = 0; e < 4; ++e) {
                const int j = j0 + e;
                // tril index j -> (ri, ci); exact at row starts since 8*tri(r)+1=(2r+1)^2
                int ri = (int)((sqrtf(8.0f * (float)j + 1.0f) - 1.0f) * 0.5f);
                if ((ri + 1) * (ri + 2) / 2 <= j) ++ri;
                if (ri * (ri + 1) / 2 > j) --ri;
                const int ci = j - ri * (ri + 1) / 2;
                const bool isdiag = (ci == ri);
                #pragma unroll
                for (int rr = 0; rr < 4; ++rr) {
                    float v = (e == 0) ? a[rr].x : (e == 1) ? a[rr].y
                            : (e == 2) ? a[rr].z : a[rr].w;
                    v = leaky(v);
                    if (isdiag) {
                        float sp = v > 20.0f ? v : log1pf(__expf(v));
                        v = fminf(fmaxf(sp, 0.001f), 100.0f) + 0.01f;
                    }
                    L_sh[rh*4 + rr][ri * LSTR + ci] = v;
                }
            }
        }
        __syncthreads();

        // --- 3b: cov[i][k] = sum_{j<=min(i,k)} L[i][j]*L[k][j] (+0.01 on diag) ---
        {
            const int lr = t >> 5;    // 0..7: which batch row of the sub-batch
            const int i  = t & 31;    // cov output row
            const float* __restrict__ Lrow = &L_sh[lr][0];

            float Li[LATENT];
            #pragma unroll
            for (int j = 0; j < LATENT; ++j) {
                const float v = Lrow[i * LSTR + j];   // in-bounds; garbage masked below
                Li[j] = (j <= i) ? v : 0.0f;
            }

            float cr[LATENT];
            #pragma unroll
            for (int k = 0; k < LATENT; ++k) {
                float a = 0.0f;
                const float* __restrict__ Lk = Lrow + k * LSTR;
                #pragma unroll
                for (int q = 0; 4 * q <= k; ++q) {
                    const float4 w = *(const float4*)(Lk + 4 * q);  // broadcast read
                    if (4*q + 0 <= k) a += Li[4*q+0] * w.x;
                    if (4*q + 1 <= k) a += Li[4*q+1] * w.y;
                    if (4*q + 2 <= k) a += Li[4*q+2] * w.z;
                    if (4*q + 3 <= k) a += Li[4*q+3] * w.w;
                }
                cr[k] = (k == i) ? a + 0.01f : a;
            }

            const size_t grow = (size_t)(row0 + rbl + lr);
            float4* __restrict__ cp =
                (float4*)(cov_out + grow * (size_t)(LATENT * LATENT) + (size_t)i * LATENT);
            #pragma unroll
            for (int k4 = 0; k4 < 8; ++k4)
                cp[k4] = make_float4(cr[4*k4+0], cr[4*k4+1], cr[4*k4+2], cr[4*k4+3]);
        }
        __syncthreads();
    }
}

extern "C" void kernel_launch(void* const* d_in, const int* in_sizes, int n_in,
                              void* d_out, int out_size, void* d_ws, size_t ws_size,
                              hipStream_t stream) {
    const float* x        = (const float*)d_in[0];
    const float* W_enc    = (const float*)d_in[1];
    const float* b_enc    = (const float*)d_in[2];
    const float* bn_gamma = (const float*)d_in[3];
    const float* bn_beta  = (const float*)d_in[4];
    const float* bn_mean  = (const float*)d_in[5];
    const float* bn_var   = (const float*)d_in[6];
    const float* W_mu     = (const float*)d_in[7];
    const float* b_mu     = (const float*)d_in[8];
    const float* W_ch     = (const float*)d_in[9];
    const float* b_ch     = (const float*)d_in[10];
    float* out = (float*)d_out;

    pm_fused<<<dim3(BATCH / RPB), dim3(256), 0, stream>>>(
        x, W_enc, b_enc, bn_gamma, bn_beta, bn_mean, bn_var,
        W_mu, b_mu, W_ch, b_ch, out);
}